// Round 9
// baseline (1526.701 us; speedup 1.0000x reference)
//
#include <hip/hip_runtime.h>
#include <initializer_list>
#include <cstdint>
#include <cstddef>

// CommCellInnerRNN on MI355X — round 8:
//  k_gemm K-loop rewritten as 2-phase double-buffered pipeline (T3-minimum):
//    prologue STAGE(0,buf0); barrier
//    loop i: STAGE(i+1, buf^1)  [issued BEFORE compute]
//            ds_read+MFMA from buf
//            __syncthreads()    [one barrier/K-step; vmcnt drain covered by MFMA]
//  Everything else (fused LSTM epilogue, gate-interleaved weights, BK=64,
//  8-slot XOR swizzle, h-carry ping-pong) unchanged from round 6.

typedef short short8 __attribute__((ext_vector_type(8)));
typedef float f32x4 __attribute__((ext_vector_type(4)));
typedef unsigned short us;

#define N_AG 4096

__device__ __forceinline__ us f2bf(float x) {
  unsigned int u = __float_as_uint(x);
  unsigned int r = (u + 0x7fffu + ((u >> 16) & 1u)) >> 16;  // RNE
  return (us)r;
}
__device__ __forceinline__ float sigm(float x) { return 1.f / (1.f + __expf(-x)); }
__device__ __forceinline__ float tanh_f(float x) {
  float e = __expf(2.f * x);
  return 1.f - 2.f / (1.f + e);
}

struct Pair { const us* A; const us* B; int K; };
struct GemmArgs {
  Pair pr[2]; int np; int N; int nunits;
  const float* bias;    // orig-ordered bias [gate*nunits+u]; used if base2==null
  const float* base2;   // full fp32 base (F1, interleaved cols), else null
  const float* cin;     // c_old  [row*nunits+u]
  float* cout;          // c_new  (null: don't store)
  const float* hold;    // h_old for mask keep (null: hn = nh)
  float* hout;          // h_new fp32 (null: skip)
  us* hb;               // h_new bf16 (always written)
  us* nhb;              // pre-mask nh bf16 (null: skip)
  const int* pres; int tt;  // tt=-1: no mask; tt==16: mask forced true
  float* C; int mode;       // mode 0: plain C=acc+bias (F1); mode 1: LSTM
};

typedef __attribute__((address_space(1))) const unsigned int as1u;
typedef __attribute__((address_space(3))) unsigned int as3u;
__device__ __forceinline__ void gload16(const void* g, void* l) {
  __builtin_amdgcn_global_load_lds((as1u*)g, (as3u*)l, 16, 0, 0);
}

__global__ __launch_bounds__(256) void k_gemm(GemmArgs g) {
  __shared__ __align__(16) us lA[2][128 * 64];   // double-buffered: 128 rows x 128B each
  __shared__ __align__(16) us lB[2][128 * 64];
  const int t = threadIdx.x;
  const int w = t >> 6, l = t & 63;
  const int bm = blockIdx.y, bn = blockIdx.x;
  const int wm = w & 1, wn = w >> 1;
  const int fr = l & 15, ks = l >> 4;
  f32x4 acc[4][4] = {};

  const int nk0 = g.pr[0].K >> 6;
  const int nt = nk0 + ((g.np > 1) ? (g.pr[1].K >> 6) : 0);

  auto stage = [&](int i, int buf) {
    const int p = (i < nk0) ? 0 : 1;
    const int kk = ((i < nk0) ? i : i - nk0) << 6;
    const int K = g.pr[p].K;
    const us* Ab = g.pr[p].A + (size_t)bm * 128 * K;
    const us* Bb = g.pr[p].B + (size_t)bn * 128 * K;
#pragma unroll
    for (int r0 = 0; r0 < 4; ++r0) {
      const int srow = r0 * 32 + (t >> 3);
      const int sslot = (t & 7) ^ (srow & 7);   // inverse-swizzled source slot
      gload16(Ab + (size_t)srow * K + kk + sslot * 8, (char*)lA[buf] + r0 * 4096 + w * 1024);
      gload16(Bb + (size_t)srow * K + kk + sslot * 8, (char*)lB[buf] + r0 * 4096 + w * 1024);
    }
  };

  stage(0, 0);
  __syncthreads();          // vmcnt(0): buf0 ready
  int cur = 0;
  for (int i = 0; i < nt; ++i) {
    if (i + 1 < nt) stage(i + 1, cur ^ 1);   // issue next-tile loads FIRST
#pragma unroll
    for (int kh = 0; kh < 2; ++kh) {
      short8 af[4], bf[4];
#pragma unroll
      for (int mi = 0; mi < 4; ++mi) {
        const int row = wm * 64 + mi * 16 + fr;
        const int s = kh * 4 + ks;
        af[mi] = *(const short8*)((const char*)lA[cur] + row * 128 + ((s ^ (row & 7)) << 4));
      }
#pragma unroll
      for (int ni = 0; ni < 4; ++ni) {
        const int row = wn * 64 + ni * 16 + fr;
        const int s = kh * 4 + ks;
        bf[ni] = *(const short8*)((const char*)lB[cur] + row * 128 + ((s ^ (row & 7)) << 4));
      }
#pragma unroll
      for (int mi = 0; mi < 4; ++mi)
#pragma unroll
        for (int ni = 0; ni < 4; ++ni)
          acc[mi][ni] = __builtin_amdgcn_mfma_f32_16x16x32_bf16(af[mi], bf[ni], acc[mi][ni], 0, 0, 0);
    }
    __syncthreads();        // drains vmcnt (next buf staged) + lgkm; one barrier/K-step
    cur ^= 1;
  }

  const int N = g.N, nu = g.nunits;
  const int u = (bn * 2 + wn) * 16 + fr;          // unit owned by this thread
  if (g.mode == 0) {
#pragma unroll
    for (int mi = 0; mi < 4; ++mi)
#pragma unroll
      for (int ni = 0; ni < 4; ++ni)
#pragma unroll
        for (int rr = 0; rr < 4; ++rr) {
          const int grow = bm * 128 + wm * 64 + mi * 16 + ks * 4 + rr;
          const int col = bn * 128 + wn * 64 + ni * 16 + fr;
          g.C[(size_t)grow * N + col] = acc[mi][ni][rr] + g.bias[ni * nu + u];
        }
    return;
  }
  // LSTM epilogue: acc[mi][0..3] = gates i,f,g,o of unit u
  float bi = 0.f, bfg = 0.f, bg = 0.f, bo = 0.f;
  if (!g.base2) { bi = g.bias[u]; bfg = g.bias[nu + u]; bg = g.bias[2 * nu + u]; bo = g.bias[3 * nu + u]; }
#pragma unroll
  for (int mi = 0; mi < 4; ++mi) {
#pragma unroll
    for (int rr = 0; rr < 4; ++rr) {
      const int grow = bm * 128 + wm * 64 + mi * 16 + ks * 4 + rr;
      float zi = acc[mi][0][rr], zf = acc[mi][1][rr], zg = acc[mi][2][rr], zo = acc[mi][3][rr];
      if (g.base2) {
        const float* fb = g.base2 + (size_t)grow * N + bn * 128 + wn * 64 + fr;
        zi += fb[0]; zf += fb[16]; zg += fb[32]; zo += fb[48];
      } else {
        zi += bi; zf += bfg; zg += bg; zo += bo;
      }
      const size_t off = (size_t)grow * nu + u;
      const float cold = g.cin[off];
      const float nc = sigm(zf) * cold + sigm(zi) * tanh_f(zg);
      const float nh = sigm(zo) * tanh_f(nc);
      bool m = true;
      if (g.tt >= 0 && g.tt < 16) m = (g.pres[grow * 48 + 3 * g.tt] >= 0);
      const float cn = m ? nc : cold;
      float hn = nh;
      if (g.hold) hn = m ? nh : g.hold[off];
      if (g.cout) g.cout[off] = cn;
      if (g.hout) g.hout[off] = hn;
      g.hb[off] = f2bf(hn);
      if (g.nhb) g.nhb[off] = f2bf(nh);
    }
  }
}

// weight transpose + gate-interleave: src (Krows x Nout) -> dst (Nout x Kpad)
// new column col <=> (gate=(col>>4)&3, u=((col>>6)<<4)|(col&15)); orig = gate*nunits+u
__global__ __launch_bounds__(256) void k_transpose(const float* __restrict__ src,
    int Nout, int nunits, int Kreal, int Kpad, int roff, us* __restrict__ dst) {
  int idx = blockIdx.x * 256 + threadIdx.x;
  if (idx >= Nout * Kpad) return;
  int col = idx % Nout;
  int k = idx / Nout;
  int gate = (col >> 4) & 3;
  int u = ((col >> 6) << 4) | (col & 15);
  float v = (k < Kreal) ? src[(size_t)(roff + k) * Nout + gate * nunits + u] : 0.f;
  dst[(size_t)col * Kpad + k] = f2bf(v);
}

__global__ __launch_bounds__(256) void k_split(const float* __restrict__ src, int n,
    float* __restrict__ f, us* __restrict__ b) {
  int idx = blockIdx.x * 256 + threadIdx.x;
  if (idx >= n) return;
  float v = src[idx];
  if (f) f[idx] = v;
  if (b) b[idx] = f2bf(v);
}

// per-step varying input: [gather(256) | onehot(4) | dist(1) | 0pad(59)] -> 320 cols
__global__ __launch_bounds__(256) void k_xvar(const int* __restrict__ pi,
    const float* __restrict__ sig, int t, us* __restrict__ xb) {
  int idx = blockIdx.x * 256 + threadIdx.x;
  if (idx >= N_AG * 320) return;
  int n = idx / 320, c = idx - n * 320;
  float v = 0.f;
  if (t < 16) {
    int p = pi[n * 48 + 3 * t];
    if (c < 256) v = (p >= 0) ? sig[(size_t)p * 256 + c] : 0.f;
    else if (c < 260) v = ((c - 256) == pi[n * 48 + 3 * t + 2]) ? 1.f : 0.f;
    else if (c == 260) v = (float)pi[n * 48 + 3 * t + 1];
  } else {
    if (c < 256) v = sig[(size_t)n * 256 + c];  // self row
  }
  xb[idx] = f2bf(v);
}

__global__ __launch_bounds__(256) void k_out(const float* __restrict__ h2,
    const float* __restrict__ feat, float* __restrict__ out) {
  int idx = blockIdx.x * 256 + threadIdx.x;
  if (idx >= N_AG * 1024) return;
  int n = idx >> 10, cc = idx & 1023;
  out[idx] = (cc < 512) ? h2[(size_t)n * 256 + (cc & 255)] : feat[(size_t)n * 512 + cc - 512];
}

// ---------- host ----------
extern "C" void kernel_launch(void* const* d_in, const int* in_sizes, int n_in,
                              void* d_out, int out_size, void* d_ws, size_t ws_size,
                              hipStream_t stream) {
  const float* inputs  = (const float*)d_in[0];
  const int*   pres    = (const int*)d_in[1];
  const float* rnn_h1  = (const float*)d_in[2];
  const float* rnn_c1  = (const float*)d_in[3];
  const float* rnn_h2  = (const float*)d_in[4];
  const float* rnn_c2  = (const float*)d_in[5];
  const float* comm_h1 = (const float*)d_in[6];
  const float* comm_c1 = (const float*)d_in[7];
  const float* comm_h2 = (const float*)d_in[8];
  const float* comm_c2 = (const float*)d_in[9];
  const float* signals = (const float*)d_in[10];
  const float* Wx1 = (const float*)d_in[11];
  const float* Wh1 = (const float*)d_in[12];
  const float* b1  = (const float*)d_in[13];
  const float* Wx2 = (const float*)d_in[14];
  const float* Wh2 = (const float*)d_in[15];
  const float* b2  = (const float*)d_in[16];
  const float* CWx1 = (const float*)d_in[17];
  const float* CWh1 = (const float*)d_in[18];
  const float* Cb1  = (const float*)d_in[19];
  const float* CWx2 = (const float*)d_in[20];
  const float* CWh2 = (const float*)d_in[21];
  const float* Cb2  = (const float*)d_in[22];
  float* out = (float*)d_out;
  (void)in_sizes; (void)n_in; (void)out_size;

  char* wsb = (char*)d_ws;
  size_t off = 0;
  auto alloc = [&](size_t bytes) -> char* {
    char* p = wsb + off;
    off = (off + bytes + 255) & ~(size_t)255;
    return p;
  };
  // interleaved transposed bf16 weights (Nout x Kpad)
  us* wx1t  = (us*)alloc(2048 * 512 * 2);
  us* wh1t  = (us*)alloc(2048 * 512 * 2);
  us* wx2t  = (us*)alloc(2048 * 512 * 2);
  us* wh2t  = (us*)alloc(2048 * 512 * 2);
  us* cx1vt = (us*)alloc(2048 * 320 * 2);
  us* cx1ft = (us*)alloc(2048 * 512 * 2);
  us* ch1t  = (us*)alloc(2048 * 512 * 2);
  us* cx2t  = (us*)alloc(1024 * 512 * 2);
  us* ch2t  = (us*)alloc(1024 * 256 * 2);
  // bf16 activations
  us* in_b   = (us*)alloc(4096 * 512 * 2);
  us* rh1_b  = (us*)alloc(4096 * 512 * 2);
  us* rh2_b  = (us*)alloc(4096 * 512 * 2);
  us* h1p_b  = (us*)alloc(4096 * 512 * 2);
  us* ft_b   = (us*)alloc(4096 * 512 * 2);
  us* h1b0   = (us*)alloc(4096 * 512 * 2);
  us* h1b1   = (us*)alloc(4096 * 512 * 2);
  us* nh1_b  = (us*)alloc(4096 * 512 * 2);
  us* h2b0   = (us*)alloc(4096 * 256 * 2);
  us* h2b1   = (us*)alloc(4096 * 256 * 2);
  us* xv_b   = (us*)alloc(4096 * 320 * 2);
  // fp32 buffers
  float* feat = (float*)alloc(4096 * 512 * 4);
  float* F1   = (float*)alloc((size_t)4096 * 2048 * 4);
  float* h1 = (float*)alloc(4096 * 512 * 4);
  float* c1 = (float*)alloc(4096 * 512 * 4);
  float* h2 = (float*)alloc(4096 * 256 * 4);
  float* c2 = (float*)alloc(4096 * 256 * 4);
  if (off > ws_size) return;

  auto tsp = [&](const float* src, int Nout, int Kreal, int Kpad, int roff, us* dst) {
    int tot = Nout * Kpad;
    k_transpose<<<dim3((tot + 255) / 256), dim3(256), 0, stream>>>(src, Nout, Nout / 4, Kreal, Kpad, roff, dst);
  };
  tsp(Wx1, 2048, 512, 512, 0, wx1t);
  tsp(Wh1, 2048, 512, 512, 0, wh1t);
  tsp(Wx2, 2048, 512, 512, 0, wx2t);
  tsp(Wh2, 2048, 512, 512, 0, wh2t);
  tsp(CWx1, 2048, 261, 320, 0, cx1vt);     // varying rows 0..260 -> Kpad 320
  tsp(CWx1, 2048, 512, 512, 261, cx1ft);   // feature rows 261..772
  tsp(CWh1, 2048, 512, 512, 0, ch1t);
  tsp(CWx2, 1024, 512, 512, 0, cx2t);
  tsp(CWh2, 1024, 256, 256, 0, ch2t);

  auto spl = [&](const float* src, int n, float* f, us* b) {
    k_split<<<dim3((n + 255) / 256), dim3(256), 0, stream>>>(src, n, f, b);
  };
  spl(inputs, 4096 * 512, nullptr, in_b);
  spl(rnn_h1, 4096 * 512, nullptr, rh1_b);
  spl(rnn_h2, 4096 * 512, nullptr, rh2_b);
  spl(comm_h1, 4096 * 512, h1, h1b0);
  spl(comm_c1, 4096 * 512, c1, nullptr);
  spl(comm_h2, 4096 * 256, h2, h2b0);
  spl(comm_c2, 4096 * 256, c2, nullptr);

  auto launch = [&](GemmArgs& ga) {
    k_gemm<<<dim3(ga.N / 128, 4096 / 128), dim3(256), 0, stream>>>(ga);
  };
  auto lstm = [&](std::initializer_list<Pair> ps, int Ncols, const float* bias, const float* base2,
                  const float* cin, float* cout, const float* hold, float* hout,
                  us* hb, us* nhb, const int* pm, int tt) {
    GemmArgs ga{};
    int i = 0;
    for (auto& p : ps) ga.pr[i++] = p;
    ga.np = i; ga.N = Ncols; ga.nunits = Ncols / 4;
    ga.bias = bias; ga.base2 = base2; ga.cin = cin; ga.cout = cout;
    ga.hold = hold; ga.hout = hout; ga.hb = hb; ga.nhb = nhb;
    ga.pres = pm; ga.tt = tt; ga.C = nullptr; ga.mode = 1;
    launch(ga);
  };
  auto plain = [&](std::initializer_list<Pair> ps, int Ncols, const float* bias, float* C) {
    GemmArgs ga{};
    int i = 0;
    for (auto& p : ps) ga.pr[i++] = p;
    ga.np = i; ga.N = Ncols; ga.nunits = Ncols / 4;
    ga.bias = bias; ga.C = C; ga.mode = 0; ga.tt = -1;
    launch(ga);
  };

  // ---- phase 1 ----
  lstm({{in_b, wx1t, 512}, {rh1_b, wh1t, 512}}, 2048, b1, nullptr,
       rnn_c1, nullptr, nullptr, nullptr, h1p_b, nullptr, nullptr, -1);
  lstm({{h1p_b, wx2t, 512}, {rh2_b, wh2t, 512}}, 2048, b2, nullptr,
       rnn_c2, nullptr, nullptr, feat, ft_b, nullptr, nullptr, -1);
  plain({{ft_b, cx1ft, 512}}, 2048, Cb1, F1);

  // ---- comm scan (h*_b ping-pong: step t reads [t&1], writes [(t+1)&1]) ----
  us* h1bp[2] = {h1b0, h1b1};
  us* h2bp[2] = {h2b0, h2b1};
  for (int t = 0; t < 17; ++t) {
    const int rd = t & 1, wr = rd ^ 1;
    k_xvar<<<dim3((4096 * 320 + 255) / 256), dim3(256), 0, stream>>>(pres, signals, t, xv_b);
    lstm({{xv_b, cx1vt, 320}, {h1bp[rd], ch1t, 512}}, 2048, nullptr, F1,
         c1, c1, h1, h1, h1bp[wr], nh1_b, pres, t);
    lstm({{nh1_b, cx2t, 512}, {h2bp[rd], ch2t, 256}}, 1024, Cb2, nullptr,
         c2, c2, h2, h2, h2bp[wr], nullptr, pres, t);
  }
  k_out<<<dim3(4096 * 1024 / 256), dim3(256), 0, stream>>>(h2, feat, out);
}